// Round 1
// baseline (430.716 us; speedup 1.0000x reference)
//
#include <hip/hip_runtime.h>

typedef unsigned short u16;
typedef unsigned int   u32;
typedef __bf16 bf16x8 __attribute__((ext_vector_type(8)));
typedef float  f32x4  __attribute__((ext_vector_type(4)));

#define M_TOT 16384
#define K_TOT 768
#define N_TOT 2304

__device__ __forceinline__ u16 f32_to_bf16(float f) {
  u32 u = __float_as_uint(f);
  u32 r = (u + 0x7FFFu + ((u >> 16) & 1u)) >> 16;  // RTNE
  return (u16)r;
}
__device__ __forceinline__ float bf16_to_f32(u16 h) {
  return __uint_as_float(((u32)h) << 16);
}

__device__ __forceinline__ void gload_lds16(const void* gsrc, void* lds) {
  __builtin_amdgcn_global_load_lds(
      (const __attribute__((address_space(1))) void*)gsrc,
      (__attribute__((address_space(3))) void*)lds, 16, 0, 0);
}

// ---------- kernel 1: per-task Frobenius sum-of-squares of the 4 adapter stacks ----------
__global__ void norms_kernel(const float* __restrict__ Aq, const float* __restrict__ Bq,
                             const float* __restrict__ Av, const float* __restrict__ Bv,
                             float* __restrict__ sumsq) {
  int b = blockIdx.x;  // 0..39 : which*10 + t
  int which = b / 10, t = b % 10;
  const float* src =
      (which == 0 ? Aq : which == 1 ? Bq : which == 2 ? Av : Bv) + t * 12288;
  float s = 0.f;
  for (int i = threadIdx.x; i < 12288; i += 256) { float v = src[i]; s += v * v; }
  for (int off = 32; off > 0; off >>= 1) s += __shfl_down(s, off, 64);
  __shared__ float red[4];
  if ((threadIdx.x & 63) == 0) red[threadIdx.x >> 6] = s;
  __syncthreads();
  if (threadIdx.x == 0) sumsq[b] = red[0] + red[1] + red[2] + red[3];
}

// ---------- kernel 2: softmax gate -> folded per-task weights wq/wv ----------
__global__ void weights_kernel(const float* __restrict__ logits, const float* __restrict__ alpha,
                               const float* __restrict__ sumsq,
                               float* __restrict__ wq, float* __restrict__ wv) {
  int t = threadIdx.x;
  if (t >= 10) return;
  float m = -1e30f;
  for (int i = 0; i < 10; ++i) m = fmaxf(m, logits[i]);
  float sum = 0.f;
  for (int i = 0; i < 10; ++i) sum += expf(logits[i] - m);   // TAU = 1.0
  float coef = (expf(logits[t] - m) / sum) * alpha[t];
  wq[t] = coef / (sqrtf(sumsq[t])      * sqrtf(sumsq[10 + t]) + 1e-8f);
  wv[t] = coef / (sqrtf(sumsq[20 + t]) * sqrtf(sumsq[30 + t]) + 1e-8f);
}

// ---------- kernel 3: build W_eff[n][k] = qkv_w[n][k] + LoRA delta, split to bf16 hi/lo ----------
// tile: 32 n-rows x 64 k-cols ; grid (12 k-tiles, 72 n-tiles)
__global__ __launch_bounds__(256) void build_weff(
    const float* __restrict__ qkv_w,
    const float* __restrict__ Aq, const float* __restrict__ Bq,
    const float* __restrict__ Av, const float* __restrict__ Bv,
    const float* __restrict__ wq, const float* __restrict__ wv,
    u16* __restrict__ Whi, u16* __restrict__ Wlo) {
  __shared__ float As[160][64];   // [(t*16+r)][k_local]
  __shared__ float Bs[160][32];   // [(t*16+r)][n_local]
  __shared__ float wsh[16];

  const int k0 = blockIdx.x * 64;
  const int n0 = blockIdx.y * 32;
  const int tid = threadIdx.x;
  const int nl = tid >> 3;        // 0..31
  const int kg = tid & 7;         // 8 consecutive k each

  float acc[8] = {0, 0, 0, 0, 0, 0, 0, 0};
  const bool is_q = (n0 < 768);
  const bool is_v = (n0 >= 1536);
  if (is_q || is_v) {
    const float* A  = is_q ? Aq : Av;
    const float* Bm = is_q ? Bq : Bv;
    const float* w  = is_q ? wq : wv;
    const int noff = is_q ? n0 : (n0 - 1536);
    for (int i = tid; i < 10240; i += 256)              // A[t][r][k0+kl]
      As[i >> 6][i & 63] = A[(i >> 6) * 768 + k0 + (i & 63)];
    for (int i = tid; i < 5120; i += 256) {             // B[t][noff+n][r]
      int tr = i >> 5, n = i & 31;
      Bs[tr][n] = Bm[(tr >> 4) * 12288 + (noff + n) * 16 + (tr & 15)];
    }
    if (tid < 10) wsh[tid] = w[tid];
    __syncthreads();
    for (int tr = 0; tr < 160; ++tr) {
      float wb = wsh[tr >> 4] * Bs[tr][nl];
#pragma unroll
      for (int j = 0; j < 8; ++j) acc[j] += wb * As[tr][kg * 8 + j];
    }
  }
  const int n = n0 + nl;
  const size_t base = (size_t)n * 768 + k0 + kg * 8;
#pragma unroll
  for (int j = 0; j < 8; ++j) {
    float v = qkv_w[base + j] + acc[j];
    u16 h = f32_to_bf16(v);
    u16 l = f32_to_bf16(v - bf16_to_f32(h));
    Whi[base + j] = h;
    Wlo[base + j] = l;
  }
}

// ---------- kernel 4: split x into bf16 hi/lo ----------
__global__ void split_x(const float* __restrict__ x, u16* __restrict__ Xhi, u16* __restrict__ Xlo) {
  int i4 = blockIdx.x * 256 + threadIdx.x;  // float4 index, 3145728 total
  if (i4 >= 3145728) return;
  float4 v = ((const float4*)x)[i4];
  u32 h0 = f32_to_bf16(v.x), h1 = f32_to_bf16(v.y), h2 = f32_to_bf16(v.z), h3 = f32_to_bf16(v.w);
  u32 l0 = f32_to_bf16(v.x - bf16_to_f32((u16)h0));
  u32 l1 = f32_to_bf16(v.y - bf16_to_f32((u16)h1));
  u32 l2 = f32_to_bf16(v.z - bf16_to_f32((u16)h2));
  u32 l3 = f32_to_bf16(v.w - bf16_to_f32((u16)h3));
  ((uint2*)Xhi)[i4] = make_uint2(h0 | (h1 << 16), h2 | (h3 << 16));
  ((uint2*)Xlo)[i4] = make_uint2(l0 | (l1 << 16), l2 | (l3 << 16));
}

// ---------- kernel 5: split-bf16 GEMM  out = X @ W^T + b ----------
// 128x128 tile, BK=32, 4 waves, global_load_lds staging with XOR slot swizzle.
// LDS row = 32 bf16 = 64 B = 4 slots of 16 B; logical slot s lives at physical s^(row&3).
__global__ __launch_bounds__(256) void gemm_split3(
    const u16* __restrict__ Xhi, const u16* __restrict__ Xlo,
    const u16* __restrict__ Whi, const u16* __restrict__ Wlo,
    const float* __restrict__ bias, float* __restrict__ out) {
  __shared__ __align__(16) u16 lds[4 * 128 * 32];  // xs_hi | xs_lo | ws_hi | ws_lo
  u16* xs_hi = lds;
  u16* xs_lo = lds + 4096;
  u16* ws_hi = lds + 8192;
  u16* ws_lo = lds + 12288;

  const int tid  = threadIdx.x;
  const int lane = tid & 63;
  const int wid  = tid >> 6;
  const int m0 = blockIdx.y << 7;
  const int n0 = blockIdx.x << 7;
  const int wm = ((wid >> 1) & 1) << 6;
  const int wn = (wid & 1) << 6;

  // staging: idx = it*256 + tid ; row = idx>>2, slot = idx&3 ; src elem = row*768 + (slot^(row&3))*8
  const int idxA = tid, idxB = tid + 256;
  const int rA = idxA >> 2, sA = idxA & 3;
  const int rB = idxB >> 2, sB = idxB & 3;
  const size_t offXA = (size_t)(m0 + rA) * 768 + ((sA ^ (rA & 3)) << 3);
  const size_t offXB = (size_t)(m0 + rB) * 768 + ((sB ^ (rB & 3)) << 3);
  const size_t offWA = (size_t)(n0 + rA) * 768 + ((sA ^ (rA & 3)) << 3);
  const size_t offWB = (size_t)(n0 + rB) * 768 + ((sB ^ (rB & 3)) << 3);
  const int ldsA = wid * 512;         // ushort index of this wave's chunk, issue 0
  const int ldsB = wid * 512 + 2048;  // issue 1

  // fragment read offsets (ushort index): r*32 + ((s ^ (r&3))*8)
  const int fl = lane & 15, fs = lane >> 4;
  int aoff[4], boff[4];
#pragma unroll
  for (int i = 0; i < 4; ++i) {
    int rm = wm + i * 16 + fl;
    aoff[i] = rm * 32 + ((fs ^ (rm & 3)) << 3);
    int rn = wn + i * 16 + fl;
    boff[i] = rn * 32 + ((fs ^ (rn & 3)) << 3);
  }

  f32x4 acc[4][4] = {};

  for (int step = 0; step < 24; ++step) {
    const int k0 = step << 5;
    gload_lds16(Xhi + offXA + k0, xs_hi + ldsA);
    gload_lds16(Xhi + offXB + k0, xs_hi + ldsB);
    gload_lds16(Xlo + offXA + k0, xs_lo + ldsA);
    gload_lds16(Xlo + offXB + k0, xs_lo + ldsB);
    gload_lds16(Whi + offWA + k0, ws_hi + ldsA);
    gload_lds16(Whi + offWB + k0, ws_hi + ldsB);
    gload_lds16(Wlo + offWA + k0, ws_lo + ldsA);
    gload_lds16(Wlo + offWB + k0, ws_lo + ldsB);
    __syncthreads();  // drains vmcnt before any wave reads LDS

    bf16x8 ah[4], al[4], bh[4], bl[4];
#pragma unroll
    for (int i = 0; i < 4; ++i) {
      ah[i] = *(const bf16x8*)(xs_hi + aoff[i]);
      al[i] = *(const bf16x8*)(xs_lo + aoff[i]);
      bh[i] = *(const bf16x8*)(ws_hi + boff[i]);
      bl[i] = *(const bf16x8*)(ws_lo + boff[i]);
    }
#pragma unroll
    for (int i = 0; i < 4; ++i)
#pragma unroll
      for (int j = 0; j < 4; ++j) {
        acc[i][j] = __builtin_amdgcn_mfma_f32_16x16x32_bf16(ah[i], bh[j], acc[i][j], 0, 0, 0);
        acc[i][j] = __builtin_amdgcn_mfma_f32_16x16x32_bf16(ah[i], bl[j], acc[i][j], 0, 0, 0);
        acc[i][j] = __builtin_amdgcn_mfma_f32_16x16x32_bf16(al[i], bh[j], acc[i][j], 0, 0, 0);
      }
    __syncthreads();  // reads done before next stage overwrites
  }

  // epilogue: C/D layout col = lane&15, row = (lane>>4)*4 + reg  [HW-verified]
#pragma unroll
  for (int j = 0; j < 4; ++j) {
    const int n = n0 + wn + j * 16 + fl;
    const float bj = bias[n];
#pragma unroll
    for (int i = 0; i < 4; ++i) {
      const int mbase = m0 + wm + i * 16 + (fs << 2);
#pragma unroll
      for (int r = 0; r < 4; ++r)
        out[(size_t)(mbase + r) * N_TOT + n] = acc[i][j][r] + bj;
    }
  }
}

extern "C" void kernel_launch(void* const* d_in, const int* in_sizes, int n_in,
                              void* d_out, int out_size, void* d_ws, size_t ws_size,
                              hipStream_t stream) {
  const float* x     = (const float*)d_in[0];
  const float* Aq    = (const float*)d_in[1];
  const float* Bq    = (const float*)d_in[2];
  const float* Av    = (const float*)d_in[3];
  const float* Bv    = (const float*)d_in[4];
  const float* qkvw  = (const float*)d_in[5];
  const float* qkvb  = (const float*)d_in[6];
  const float* gate  = (const float*)d_in[7];
  const float* alpha = (const float*)d_in[8];
  float* out = (float*)d_out;

  char* ws = (char*)d_ws;
  float* sumsq = (float*)ws;           // 40 floats
  float* wq    = (float*)(ws + 256);   // 10 floats
  float* wv    = (float*)(ws + 512);   // 10 floats
  u16* Whi = (u16*)(ws + 1024);        // 2304*768 bf16
  u16* Wlo = Whi + 1769472;
  u16* Xhi = Wlo + 1769472;            // 16384*768 bf16
  u16* Xlo = Xhi + 12582912;           // total ws use ~58 MB

  hipLaunchKernelGGL(norms_kernel,   dim3(40),      dim3(256), 0, stream, Aq, Bq, Av, Bv, sumsq);
  hipLaunchKernelGGL(weights_kernel, dim3(1),       dim3(64),  0, stream, gate, alpha, sumsq, wq, wv);
  hipLaunchKernelGGL(build_weff,     dim3(12, 72),  dim3(256), 0, stream, qkvw, Aq, Bq, Av, Bv, wq, wv, Whi, Wlo);
  hipLaunchKernelGGL(split_x,        dim3(12288),   dim3(256), 0, stream, x, Xhi, Xlo);
  hipLaunchKernelGGL(gemm_split3,    dim3(18, 128), dim3(256), 0, stream, Xhi, Xlo, Whi, Wlo, qkvb, out);
}